// Round 6
// baseline (149.823 us; speedup 1.0000x reference)
//
#include <hip/hip_runtime.h>

// SemanticCaps dynamic routing, fp32. B=128, J=10, K=1152, M=16, I=8.
// R6: W in LDS with per-lane-distinct ds_read_b128 (1 read per 8 FMA ->
// VALU-balanced), b-minor global layouts, u kept in registers between logit
// and accumulation, e exchanged via j-minor LDS rows (vector den reads),
// 2 blocks/CU occupancy. R5's scalar-path W was serialized by out-of-order
// s_load + lgkmcnt(0) drains at 1 block/CU — latency-bound.
// b-logit algebra: b after t iters = u.(v0+..+v_{t-1}) (b starts at 0).
//
// ws (floats): xT[1,179,648] sp[2,621,440] v0T[20480] vsumT[20480]

#define B_ 128
#define J_ 10
#define K_ 1152
#define M_ 16
#define I_ 8
#define KT 9
#define NKT (K_ / KT)     // 128 k-tiles
#define RW (K_ * I_)      // 9216 rows of xT
#define QS 9              // ws4 mq stride (float4), 8+1 pad
#define JS (4 * QS)       // 36
#define KS (J_ * JS + 1)  // 361 float4 per k row

__device__ __forceinline__ float dot8(float4 w0, float4 w1, float4 xa, float4 xb) {
    return w0.x * xa.x + w0.y * xa.y + w0.z * xa.z + w0.w * xa.w
         + w1.x * xb.x + w1.y * xb.y + w1.z * xb.z + w1.w * xb.w;
}

// ---------- transpose x[b][k][i] -> xT[k*8+i][b] ----------------------------
__global__ __launch_bounds__(256)
void xpose_kernel(const float* __restrict__ x, float* __restrict__ xT) {
    __shared__ float tile[64 * 65];
    const int t = threadIdx.x;
    const int r0 = blockIdx.x * 64, b0 = blockIdx.y * 64;
    const int hi = t >> 6, lo = t & 63;
#pragma unroll 4
    for (int c = 0; c < 16; ++c) {
        const int bb = c * 4 + hi;
        tile[lo * 65 + bb] = x[(size_t)(b0 + bb) * RW + r0 + lo];
    }
    __syncthreads();
#pragma unroll 4
    for (int c = 0; c < 16; ++c) {
        const int r = c * 4 + hi;
        xT[(size_t)(r0 + r) * B_ + b0 + lo] = tile[r * 65 + lo];
    }
}

// ---------- routing iteration ------------------------------------------------
// MODE 0: c == 1 (iteration 0; 0.1 folded into squash<0>)
// MODE 1: c = softmax_j(u . vin);  s = sum_k c*u  (u stays in registers)
// Block: 640 thr = 10 waves (wave = j). lane = mq*16 + bl; 2 serial b (bs).
// Grid: (128 k-tiles, 4 b-groups of 32).
template <int MODE>
__global__ __launch_bounds__(640, 5)
void iter_kernel(const float* __restrict__ xT, const float* __restrict__ Ws,
                 const float* __restrict__ vinT, float* __restrict__ sp) {
    __shared__ float4 ws4[KT * KS];                        // ~52 KB
    __shared__ float earr[MODE == 1 ? 2 * 32 * 12 : 4];    // [pp][b_loc][j(pad12)]

    const int t    = threadIdx.x;
    const int lane = t & 63;
    const int j    = __builtin_amdgcn_readfirstlane(t >> 6);
    const int mq   = lane >> 4;      // m-quad 0..3
    const int bl   = lane & 15;
    const int kt   = blockIdx.x, bg = blockIdx.y;
    const int b0   = bg * 32;        // block's batch base; thread b = b0+bs*16+bl

    // ---- stage Ws[all j][kt*9 .. +8][16m][8i] into padded LDS ----
    {
        const float4* wsg = (const float4*)Ws;
        const int k0 = kt * KT;
        for (int l = t; l < KT * J_ * 32; l += 640) {
            const int kl = l / 320, rem = l - kl * 320;
            const int jj = rem >> 5, c = rem & 31;
            ws4[kl * KS + jj * JS + (c >> 3) * QS + (c & 7)] =
                wsg[((size_t)jj * K_ + k0 + kl) * 32 + c];
        }
    }

    float4 vq[2];
    if (MODE == 1) {
#pragma unroll
        for (int bs = 0; bs < 2; ++bs)
            vq[bs] = *(const float4*)(vinT +
                       ((size_t)j * B_ + b0 + bs * 16 + bl) * M_ + mq * 4);
    }
    __syncthreads();

    float s[2][4] = {{0.f, 0.f, 0.f, 0.f}, {0.f, 0.f, 0.f, 0.f}};

#pragma unroll 1
    for (int kk = 0; kk < KT; ++kk) {
        const int k = kt * KT + kk;
        const float4* wq = ws4 + kk * KS + j * JS + mq * QS;
        const float4 w0 = wq[0], w1 = wq[1], w2 = wq[2], w3 = wq[3];
        const float4 w4 = wq[4], w5 = wq[5], w6 = wq[6], w7 = wq[7];

        float u[2][4];
        float e[2];
#pragma unroll
        for (int bs = 0; bs < 2; ++bs) {
            const int b = b0 + bs * 16 + bl;
            const float* xr = xT + (size_t)k * I_ * B_ + b;
            float4 xa, xb;
            xa.x = xr[0 * B_]; xa.y = xr[1 * B_]; xa.z = xr[2 * B_]; xa.w = xr[3 * B_];
            xb.x = xr[4 * B_]; xb.y = xr[5 * B_]; xb.z = xr[6 * B_]; xb.w = xr[7 * B_];
            u[bs][0] = dot8(w0, w1, xa, xb);
            u[bs][1] = dot8(w2, w3, xa, xb);
            u[bs][2] = dot8(w4, w5, xa, xb);
            u[bs][3] = dot8(w6, w7, xa, xb);
            if (MODE == 1) {
                float lg = u[bs][0] * vq[bs].x + u[bs][1] * vq[bs].y
                         + u[bs][2] * vq[bs].z + u[bs][3] * vq[bs].w;
                lg += __shfl_xor(lg, 16, 64);    // reduce over mq
                lg += __shfl_xor(lg, 32, 64);
                e[bs] = __expf(lg);
            } else {
#pragma unroll
                for (int p = 0; p < 4; ++p) s[bs][p] += u[bs][p];
            }
        }

        if (MODE == 1) {
            const int pp = kk & 1;
            if (mq == 0) {
                earr[(pp * 32 + bl) * 12 + j] = e[0];
                earr[(pp * 32 + 16 + bl) * 12 + j] = e[1];
            }
            __syncthreads();    // ping-pong [2] makes k+1 write / k read race-free
#pragma unroll
            for (int bs = 0; bs < 2; ++bs) {
                const float* er = &earr[(pp * 32 + bs * 16 + bl) * 12];
                const float4 d0 = *(const float4*)er;
                const float4 d1 = *(const float4*)(er + 4);
                const float den = d0.x + d0.y + d0.z + d0.w
                                + d1.x + d1.y + d1.z + d1.w + er[8] + er[9];
                const float c = __fdividef(e[bs], den);
#pragma unroll
                for (int p = 0; p < 4; ++p) s[bs][p] += c * u[bs][p];
            }
        }
    }

#pragma unroll
    for (int bs = 0; bs < 2; ++bs) {
        float4 o;
        o.x = s[bs][0]; o.y = s[bs][1]; o.z = s[bs][2]; o.w = s[bs][3];
        *(float4*)(sp + (((size_t)kt * J_ + j) * B_ + b0 + bs * 16 + bl) * M_
                   + mq * 4) = o;
    }
}

// ---------- squash: fold 128 coalesced tile-partials, emit v -----------------
// SM 0: v0T = squash(0.1*S)  SM 1: vsumT = v0T + squash(S)  SM 2: out = squash(S)
template <int SM>
__global__ __launch_bounds__(256)
void squash_kernel(const float* __restrict__ sp, const float* __restrict__ v0T,
                   float* __restrict__ dst) {
    const int g = blockIdx.x * 256 + threadIdx.x;   // g = (j*128+b)*16+m
    const int m = g & 15;
    const int b = (g >> 4) & 127;
    const int j = g >> 11;
    float S = 0.f;
#pragma unroll 8
    for (int tt = 0; tt < NKT; ++tt)
        S += sp[(((size_t)tt * J_ + j) * B_ + b) * M_ + m];
    if (SM == 0) S *= 0.1f;
    float sq = S * S;
    sq += __shfl_xor(sq, 1, 64);
    sq += __shfl_xor(sq, 2, 64);
    sq += __shfl_xor(sq, 4, 64);
    sq += __shfl_xor(sq, 8, 64);
    const float n = sqrtf(sq);
    float v = S * (n / (1.f + sq));
    if (SM == 1) v += v0T[g];
    if (SM == 2) dst[((size_t)b * J_ + j) * M_ + m] = v;   // standard [b][j][m]
    else         dst[g] = v;                                // vT layout
}

extern "C" void kernel_launch(void* const* d_in, const int* in_sizes, int n_in,
                              void* d_out, int out_size, void* d_ws, size_t ws_size,
                              hipStream_t stream) {
    const float* x  = (const float*)d_in[0];   // [128][1152][8]
    const float* Ws = (const float*)d_in[1];   // [10][1152][16][8]
    float* out = (float*)d_out;                // [128][10][16]

    float* xT    = (float*)d_ws;                           // 1,179,648
    float* sp    = xT + (size_t)RW * B_;                   // 2,621,440
    float* v0T   = sp + (size_t)NKT * J_ * B_ * M_;        //    20,480
    float* vsumT = v0T + J_ * B_ * M_;                     //    20,480

    xpose_kernel<<<dim3(RW / 64, 2), 256, 0, stream>>>(x, xT);

    const dim3 gi(NKT, 4);
    iter_kernel<0><<<gi, 640, 0, stream>>>(xT, Ws, nullptr, sp);
    squash_kernel<0><<<80, 256, 0, stream>>>(sp, nullptr, v0T);

    iter_kernel<1><<<gi, 640, 0, stream>>>(xT, Ws, v0T, sp);
    squash_kernel<1><<<80, 256, 0, stream>>>(sp, v0T, vsumT);

    iter_kernel<1><<<gi, 640, 0, stream>>>(xT, Ws, vsumT, sp);
    squash_kernel<2><<<80, 256, 0, stream>>>(sp, nullptr, out);
}